// Round 3
// baseline (537.596 us; speedup 1.0000x reference)
//
#include <hip/hip_runtime.h>

#define N_NODES 131072
#define C_DIM   128
#define H_DIM   128
#define B_SEG   1024
#define M_TILE  128
#define K_TILE  32
#define YT_STR  132      // Yt row stride: 16B-aligned float4 rows
#define SEGCAP  384

// ---------------------------------------------------------------------------
// Kernel 1: per-node readout  v[n] = lin(n) + relu(x3 @ W1 + b1) @ W2 + b2
// R7: software-pipelined. Yt is double-buffered; X loads for tile it+1 are
// issued in two 8-pass half-batches UNDER the GEMM of tile it (32 VGPR of
// prefetch, consumed mid-loop), so vmcnt stalls drain beneath ~2000 cyc of
// FMA instead of in a dedicated load phase. LDS 52KB -> 3 blocks/CU;
// __launch_bounds__(256,3) raises the VGPR cap to ~168 (R3's spill was at
// the (256,4)/128-reg cap holding 16 float4s; we hold 8).
// ---------------------------------------------------------------------------
__global__ __launch_bounds__(256, 3)
void node_readout_kernel(const float* __restrict__ emb,
                         const float* __restrict__ W_lins,
                         const float* __restrict__ b_lins,
                         const float* __restrict__ W1,
                         const float* __restrict__ b1,
                         const float* __restrict__ W2,
                         const float* __restrict__ b2,
                         float* __restrict__ v_out)
{
    __shared__ float Yt[2][K_TILE * YT_STR];  // 33.8 KB double-buffered
    __shared__ float W1s[K_TILE * H_DIM];     // 16 KB (reused as nl_red)
    __shared__ float WLs[3 * C_DIM];          // 1.5 KB
    __shared__ float lin_lds[M_TILE];         // 0.5 KB

    const int t  = threadIdx.x;
    const int nbase = blockIdx.x * M_TILE;
    const int ln = t >> 5;        // 0..7 : node sub-index per pass
    const int cc = t & 31;        // float4 index within K-tile
    const int jg = t & 15;        // gemm j-group
    const int mg = t >> 4;        // gemm m-group

    for (int i = t; i < 3 * C_DIM; i += 256) WLs[i] = W_lins[i];

    float acc[8][8];
    #pragma unroll
    for (int mi = 0; mi < 8; ++mi)
        #pragma unroll
        for (int ji = 0; ji < 8; ++ji) acc[mi][ji] = 0.0f;

    float lin_p[16];
    #pragma unroll
    for (int p = 0; p < 16; ++p) lin_p[p] = 0.0f;

    const float4* xbase = (const float4*)emb + (size_t)(nbase + ln) * C_DIM;
    const float4* W1_4  = (const float4*)W1;

    // decorrelate L2 access pattern of co-resident blocks
    const int ct0 = (blockIdx.x ^ (blockIdx.x >> 8)) & 3;

    // ---- prologue: stage tile ct0 into Yt[0], W1 regs hold tile ct0 ----
    float4 wr0 = W1_4[ct0 * 1024 + t];
    float4 wr1 = W1_4[ct0 * 1024 + t + 256];
    float4 wr2 = W1_4[ct0 * 1024 + t + 512];
    float4 wr3 = W1_4[ct0 * 1024 + t + 768];
    float4 xp[8];
    #pragma unroll
    for (int p = 0; p < 8; ++p) xp[p] = xbase[p * 8 * C_DIM + ct0 * K_TILE + cc];

    __syncthreads();   // WLs ready

    {
        const int c0 = ct0 * K_TILE + cc;
        const float wl0 = WLs[c0], wl1 = WLs[C_DIM + c0], wl2 = WLs[2 * C_DIM + c0];
        #pragma unroll
        for (int p = 0; p < 8; ++p) {
            float4 x = xp[p];
            lin_p[p] = fmaf(x.x, wl0, fmaf(x.y, wl1, fmaf(x.z, wl2, lin_p[p])));
            Yt[0][cc * YT_STR + p * 8 + ln] = x.w;
        }
        #pragma unroll
        for (int p = 0; p < 8; ++p) xp[p] = xbase[(p + 8) * 8 * C_DIM + ct0 * K_TILE + cc];
        #pragma unroll
        for (int p = 0; p < 8; ++p) {
            float4 x = xp[p];
            lin_p[p + 8] = fmaf(x.x, wl0, fmaf(x.y, wl1, fmaf(x.z, wl2, lin_p[p + 8])));
            Yt[0][cc * YT_STR + (p + 8) * 8 + ln] = x.w;
        }
    }

    for (int it = 0; it < 4; ++it) {
        const int cur = it & 1;
        const int ctn = (it + 1 + ct0) & 3;    // next K-tile (prefetched)

        __syncthreads();   // prev GEMM done (W1s free), Yt[cur] fully written

        // store current W1 tile (regs from prev iter / prologue) to LDS
        {
            float4* dst = (float4*)W1s;
            dst[t]       = wr0;
            dst[t + 256] = wr1;
            dst[t + 512] = wr2;
            dst[t + 768] = wr3;
        }
        if (it < 3) {
            // issue next-tile W1 + first half of next-tile X (land under GEMM)
            wr0 = W1_4[ctn * 1024 + t];
            wr1 = W1_4[ctn * 1024 + t + 256];
            wr2 = W1_4[ctn * 1024 + t + 512];
            wr3 = W1_4[ctn * 1024 + t + 768];
            #pragma unroll
            for (int p = 0; p < 8; ++p) xp[p] = xbase[p * 8 * C_DIM + ctn * K_TILE + cc];
        }
        __syncthreads();   // W1s ready (only 4 ds_writes between barriers)

        // ---- GEMM first half: k = 0..15 ----
        #pragma unroll 8
        for (int k = 0; k < K_TILE / 2; ++k) {
            float4 ya = *(const float4*)&Yt[cur][k * YT_STR + mg * 8];
            float4 yb = *(const float4*)&Yt[cur][k * YT_STR + mg * 8 + 4];
            float w[8];
            #pragma unroll
            for (int ji = 0; ji < 8; ++ji) w[ji] = W1s[k * H_DIM + jg + 16 * ji];
            float ym[8] = {ya.x, ya.y, ya.z, ya.w, yb.x, yb.y, yb.z, yb.w};
            #pragma unroll
            for (int mi = 0; mi < 8; ++mi)
                #pragma unroll
                for (int ji = 0; ji < 8; ++ji)
                    acc[mi][ji] = fmaf(ym[mi], w[ji], acc[mi][ji]);
        }

        if (it < 3) {
            // consume X[0..7] (long landed), write other Yt buffer; issue X[8..15]
            const int c0 = ctn * K_TILE + cc;
            const float wl0 = WLs[c0], wl1 = WLs[C_DIM + c0], wl2 = WLs[2 * C_DIM + c0];
            #pragma unroll
            for (int p = 0; p < 8; ++p) {
                float4 x = xp[p];
                lin_p[p] = fmaf(x.x, wl0, fmaf(x.y, wl1, fmaf(x.z, wl2, lin_p[p])));
                Yt[cur ^ 1][cc * YT_STR + p * 8 + ln] = x.w;
            }
            #pragma unroll
            for (int p = 0; p < 8; ++p) xp[p] = xbase[(p + 8) * 8 * C_DIM + ctn * K_TILE + cc];
        }

        // ---- GEMM second half: k = 16..31 ----
        #pragma unroll 8
        for (int k = K_TILE / 2; k < K_TILE; ++k) {
            float4 ya = *(const float4*)&Yt[cur][k * YT_STR + mg * 8];
            float4 yb = *(const float4*)&Yt[cur][k * YT_STR + mg * 8 + 4];
            float w[8];
            #pragma unroll
            for (int ji = 0; ji < 8; ++ji) w[ji] = W1s[k * H_DIM + jg + 16 * ji];
            float ym[8] = {ya.x, ya.y, ya.z, ya.w, yb.x, yb.y, yb.z, yb.w};
            #pragma unroll
            for (int mi = 0; mi < 8; ++mi)
                #pragma unroll
                for (int ji = 0; ji < 8; ++ji)
                    acc[mi][ji] = fmaf(ym[mi], w[ji], acc[mi][ji]);
        }

        if (it < 3) {
            // consume X[8..15]
            const int c0 = ctn * K_TILE + cc;
            const float wl0 = WLs[c0], wl1 = WLs[C_DIM + c0], wl2 = WLs[2 * C_DIM + c0];
            #pragma unroll
            for (int p = 0; p < 8; ++p) {
                float4 x = xp[p];
                lin_p[p + 8] = fmaf(x.x, wl0, fmaf(x.y, wl1, fmaf(x.z, wl2, lin_p[p + 8])));
                Yt[cur ^ 1][cc * YT_STR + (p + 8) * 8 + ln] = x.w;
            }
        }
    }

    // reduce lin over the 32 cc lanes
    #pragma unroll
    for (int p = 0; p < 16; ++p) {
        float s = lin_p[p];
        s += __shfl_xor(s, 16);
        s += __shfl_xor(s, 8);
        s += __shfl_xor(s, 4);
        s += __shfl_xor(s, 2);
        s += __shfl_xor(s, 1);
        lin_p[p] = s;
    }
    if (cc == 0) {
        #pragma unroll
        for (int p = 0; p < 16; ++p) lin_lds[p * 8 + ln] = lin_p[p];
    }

    __syncthreads();                // GEMM reads done -> reuse W1s as nl_red
    float* nl_red = W1s;            // [m][jg] stride 17

    float b1r[8], W2r[8];
    #pragma unroll
    for (int ji = 0; ji < 8; ++ji) {
        int j = jg + 16 * ji;
        b1r[ji] = b1[j];
        W2r[ji] = W2[j];
    }

    #pragma unroll
    for (int mi = 0; mi < 8; ++mi) {
        float s = 0.0f;
        #pragma unroll
        for (int ji = 0; ji < 8; ++ji) {
            float h = acc[mi][ji] + b1r[ji];
            h = h > 0.0f ? h : 0.0f;
            s = fmaf(h, W2r[ji], s);
        }
        nl_red[(mg * 8 + mi) * 17 + jg] = s;
    }
    __syncthreads();

    if (t < M_TILE) {
        float s = lin_lds[t];
        #pragma unroll
        for (int g = 0; g < 16; ++g) s += nl_red[t * 17 + g];
        s += b_lins[0] + b_lins[1] + b_lins[2] + b2[0];
        v_out[nbase + t] = s;
    }
}

// ---------------------------------------------------------------------------
// Wave-parallel 64-ary lower_bound: each lane probes one split point,
// ballot/popc selects the sub-interval. Range shrinks 64x per round ->
// 131072 resolves in 4 dependent loads (vs 17 for binary search).
// ---------------------------------------------------------------------------
__device__ __forceinline__ int lower_bound_wave(const int* __restrict__ batch,
                                                int target, int lane)
{
    int lo = 0, hi = N_NODES;
    while (lo < hi) {
        int span  = hi - lo;
        int chunk = (span + 63) >> 6;          // ceil(span/64)
        int idx   = lo + lane * chunk;         // lane 0 probes lo
        bool p    = (idx < hi) && (batch[idx] < target);
        unsigned long long m = __ballot(p);
        int c = __popcll(m);                   // prefix-true count
        if (c == 0) return lo;                 // batch[lo] >= target
        int nhi = (c < 64) ? (lo + c * chunk) : hi;
        lo = lo + (c - 1) * chunk + 1;
        hi = (nhi < hi) ? nhi : hi;
    }
    return lo;
}

// ---------------------------------------------------------------------------
// Kernel 2: one wave per segment; rank sort; quantiles; fused final MLP.
// ---------------------------------------------------------------------------
__global__ __launch_bounds__(256)
void aggregate_kernel(const float* __restrict__ v,
                      const int* __restrict__ batch,
                      const float* __restrict__ Wm1,
                      const float* __restrict__ bm1,
                      const float* __restrict__ Wm2,
                      const float* __restrict__ bm2,
                      float* __restrict__ out)
{
    __shared__ float vals[4][SEGCAP];
    __shared__ float sorted[4][SEGCAP];
    __shared__ float agg_s[4][12];

    const int t    = threadIdx.x;
    const int wid  = t >> 6;
    const int lane = t & 63;
    const int b    = blockIdx.x * 4 + wid;

    const int start = lower_bound_wave(batch, b, lane);
    const int end   = lower_bound_wave(batch, b + 1, lane);
    int cnt = end - start;
    if (cnt > SEGCAP) cnt = SEGCAP;

    float lsum = 0.0f;
    for (int i = lane; i < cnt; i += 64) {
        float x = v[start + i];
        vals[wid][i] = x;
        lsum += x;
    }
    #pragma unroll
    for (int o = 32; o; o >>= 1) lsum += __shfl_xor(lsum, o);
    __syncthreads();

    for (int i = lane; i < cnt; i += 64) {
        float xi = vals[wid][i];
        int r = 0;
        for (int j = 0; j < cnt; ++j) {
            float xj = vals[wid][j];
            r += (xj < xi) || (xj == xi && j < i);
        }
        sorted[wid][r] = xi;
    }
    __syncthreads();

    if (cnt > 0) {
        float cntf = (float)cnt;
        if (lane == 9)  agg_s[wid][0] = lsum / cntf;
        if (lane == 10) agg_s[wid][1] = sorted[wid][cnt - 1];
        if (lane == 11) agg_s[wid][2] = sorted[wid][0];
        if (lane < 9) {
            float q   = (float)(lane + 1) * 0.1f;
            float pos = q * (cntf - 1.0f);
            float f   = floorf(pos);
            float frac = pos - f;
            int loi = (int)f;
            int hii = loi + 1; if (hii > cnt - 1) hii = cnt - 1;
            agg_s[wid][3 + lane] = sorted[wid][loi] + frac * (sorted[wid][hii] - sorted[wid][loi]);
        }
    } else {
        if (lane < 12) agg_s[wid][lane] = 0.0f;
    }
    __syncthreads();

    float term = 0.0f;
    #pragma unroll
    for (int rj = 0; rj < 2; ++rj) {
        int j = lane + 64 * rj;
        float h = bm1[j];
        #pragma unroll
        for (int k = 0; k < 12; ++k) h = fmaf(agg_s[wid][k], Wm1[k * H_DIM + j], h);
        h = h > 0.0f ? h : 0.0f;
        term = fmaf(h, Wm2[j], term);
    }
    #pragma unroll
    for (int o = 32; o; o >>= 1) term += __shfl_xor(term, o);
    if (lane == 0) out[b] = term + bm2[0];
}

// ---------------------------------------------------------------------------
extern "C" void kernel_launch(void* const* d_in, const int* in_sizes, int n_in,
                              void* d_out, int out_size, void* d_ws, size_t ws_size,
                              hipStream_t stream)
{
    const float* emb    = (const float*)d_in[0];
    const int*   batch  = (const int*)d_in[1];
    const float* W_lins = (const float*)d_in[2];
    const float* b_lins = (const float*)d_in[3];
    const float* W1     = (const float*)d_in[4];
    const float* b1     = (const float*)d_in[5];
    const float* W2     = (const float*)d_in[6];
    const float* b2     = (const float*)d_in[7];
    const float* Wm1    = (const float*)d_in[8];
    const float* bm1    = (const float*)d_in[9];
    const float* Wm2    = (const float*)d_in[10];
    const float* bm2    = (const float*)d_in[11];

    float* out  = (float*)d_out;
    float* vbuf = (float*)d_ws;   // 512 KB scratch

    node_readout_kernel<<<N_NODES / M_TILE, 256, 0, stream>>>(
        emb, W_lins, b_lins, W1, b1, W2, b2, vbuf);
    aggregate_kernel<<<B_SEG / 4, 256, 0, stream>>>(
        vbuf, batch, Wm1, bm1, Wm2, bm2, out);
}

// Round 4
// 417.219 us; speedup vs baseline: 1.2885x; 1.2885x over previous
//
#include <hip/hip_runtime.h>
#include <stdint.h>

#define N_NODES 131072
#define C_DIM   128
#define H_DIM   128
#define B_SEG   1024
#define M_TILE  128
#define K_TILE  32
#define YT_STR  132      // Yt row stride: 16B-aligned float4 rows
#define SEGCAP  384

// async 16B/lane global->LDS copy (canonical plain-HIP form)
#define GLOAD_LDS16(gaddr, laddr)                                              \
    __builtin_amdgcn_global_load_lds(                                          \
        (const __attribute__((address_space(1))) void*)(gaddr),                \
        (__attribute__((address_space(3))) void*)(laddr), 16, 0, 0)

// ---------------------------------------------------------------------------
// Kernel 1: per-node readout  v[n] = lin(n) + relu(x3 @ W1 + b1) @ W2 + b2
// R8: R6 two-barrier structure (proven; (256,4) -> 128-reg cap, no spill).
//  - W1 K-tile (contiguous 16KB row-slice) staged via global_load_lds width=16:
//    async, zero VGPR, drained by the compiler's vmcnt(0) before s_barrier.
//    (R7 lesson: __launch_bounds__(256,3) empirically caps at 84 regs -> 1.3KB/
//    thread scratch spill, 337MB scratch writes, kernel 142->256us. Never again.)
//  - Freed registers spent on a 4-deep rolling X prefetch (xp[4], full unroll,
//    static indices): compiler emits counted vmcnt(N), keeping 3-4 HBM loads
//    in flight per wave (vs ~1 in the load->use chain), 64KB in flight/CU.
// Register demand ~115 < 128 cap.
// ---------------------------------------------------------------------------
__global__ __launch_bounds__(256, 4)
void node_readout_kernel(const float* __restrict__ emb,
                         const float* __restrict__ W_lins,
                         const float* __restrict__ b_lins,
                         const float* __restrict__ W1,
                         const float* __restrict__ b1,
                         const float* __restrict__ W2,
                         const float* __restrict__ b2,
                         float* __restrict__ v_out)
{
    __shared__ float Yt[K_TILE * YT_STR];     // [cc][m] 16.9 KB
    __shared__ float W1s[K_TILE * H_DIM];     // 16 KB (reused as nl_red)
    __shared__ float WLs[3 * C_DIM];          // 1.5 KB
    __shared__ float lin_lds[M_TILE];         // 0.5 KB

    const int t  = threadIdx.x;
    const int nbase = blockIdx.x * M_TILE;
    const int ln = t >> 5;        // 0..7 : node sub-index per pass
    const int cc = t & 31;        // float4 index within K-tile
    const int jg = t & 15;        // gemm j-group
    const int mg = t >> 4;        // gemm m-group
    const int w  = t >> 6;        // wave id (for LDS-copy base)

    for (int i = t; i < 3 * C_DIM; i += 256) WLs[i] = W_lins[i];

    float acc[8][8];
    #pragma unroll
    for (int mi = 0; mi < 8; ++mi)
        #pragma unroll
        for (int ji = 0; ji < 8; ++ji) acc[mi][ji] = 0.0f;

    float lin_p[16];
    #pragma unroll
    for (int p = 0; p < 16; ++p) lin_p[p] = 0.0f;

    const float4* xbase = (const float4*)emb + (size_t)(nbase + ln) * C_DIM;

    // decorrelate L2 access pattern of co-resident blocks
    const int ct0 = (blockIdx.x ^ (blockIdx.x >> 8)) & 3;

    __syncthreads();   // WLs ready

    for (int it = 0; it < C_DIM / K_TILE; ++it) {
        const int ct = (it + ct0) & 3;
        if (it) __syncthreads();   // previous GEMM done: Yt and W1s free

        // ---- phase A: prime X prefetch, issue async W1 copy, stream X ----
        const int c0 = ct * K_TILE + cc;
        const float wl0 = WLs[c0], wl1 = WLs[C_DIM + c0], wl2 = WLs[2 * C_DIM + c0];

        float4 xp[4];
        #pragma unroll
        for (int i = 0; i < 4; ++i)
            xp[i] = xbase[i * 8 * C_DIM + ct * K_TILE + cc];

        // W1 tile = contiguous 16KB slice W1[ct*32 .. ct*32+31][*]:
        // 1024 x 16B chunks; chunk id = q*256 + t; LDS dest linear.
        {
            const char* wsrc = (const char*)(W1 + ct * (K_TILE * H_DIM));
            char*       wdst = (char*)W1s;
            #pragma unroll
            for (int q = 0; q < 4; ++q) {
                GLOAD_LDS16(wsrc + (size_t)(q * 256 + t) * 16,
                            wdst + (size_t)(q * 256 + w * 64) * 16);
            }
        }

        // rolling 4-deep prefetch over the 16 X passes (all indices static)
        #pragma unroll
        for (int p = 0; p < 16; ++p) {
            float4 x = xp[p & 3];
            if (p < 12)
                xp[p & 3] = xbase[(p + 4) * 8 * C_DIM + ct * K_TILE + cc];
            lin_p[p] = fmaf(x.x, wl0, fmaf(x.y, wl1, fmaf(x.z, wl2, lin_p[p])));
            Yt[cc * YT_STR + p * 8 + ln] = x.w;
        }

        __syncthreads();   // drains vmcnt(0): W1s + Yt ready

        // ---- phase B: register-blocked GEMM, 8m x 8j per thread ----
        #pragma unroll 8
        for (int k = 0; k < K_TILE; ++k) {
            float4 ya = *(const float4*)&Yt[k * YT_STR + mg * 8];
            float4 yb = *(const float4*)&Yt[k * YT_STR + mg * 8 + 4];
            float wv[8];
            #pragma unroll
            for (int ji = 0; ji < 8; ++ji) wv[ji] = W1s[k * H_DIM + jg + 16 * ji];
            float ym[8] = {ya.x, ya.y, ya.z, ya.w, yb.x, yb.y, yb.z, yb.w};
            #pragma unroll
            for (int mi = 0; mi < 8; ++mi)
                #pragma unroll
                for (int ji = 0; ji < 8; ++ji)
                    acc[mi][ji] = fmaf(ym[mi], wv[ji], acc[mi][ji]);
        }
    }

    // reduce lin over the 32 cc lanes
    #pragma unroll
    for (int p = 0; p < 16; ++p) {
        float s = lin_p[p];
        s += __shfl_xor(s, 16);
        s += __shfl_xor(s, 8);
        s += __shfl_xor(s, 4);
        s += __shfl_xor(s, 2);
        s += __shfl_xor(s, 1);
        lin_p[p] = s;
    }
    if (cc == 0) {
        #pragma unroll
        for (int p = 0; p < 16; ++p) lin_lds[p * 8 + ln] = lin_p[p];
    }

    __syncthreads();                // GEMM reads done -> reuse W1s as nl_red
    float* nl_red = W1s;            // [m][jg] stride 17

    float b1r[8], W2r[8];
    #pragma unroll
    for (int ji = 0; ji < 8; ++ji) {
        int j = jg + 16 * ji;
        b1r[ji] = b1[j];
        W2r[ji] = W2[j];
    }

    #pragma unroll
    for (int mi = 0; mi < 8; ++mi) {
        float s = 0.0f;
        #pragma unroll
        for (int ji = 0; ji < 8; ++ji) {
            float h = acc[mi][ji] + b1r[ji];
            h = h > 0.0f ? h : 0.0f;
            s = fmaf(h, W2r[ji], s);
        }
        nl_red[(mg * 8 + mi) * 17 + jg] = s;
    }
    __syncthreads();

    if (t < M_TILE) {
        float s = lin_lds[t];
        #pragma unroll
        for (int g = 0; g < 16; ++g) s += nl_red[t * 17 + g];
        s += b_lins[0] + b_lins[1] + b_lins[2] + b2[0];
        v_out[nbase + t] = s;
    }
}

// ---------------------------------------------------------------------------
// Wave-parallel 64-ary lower_bound: each lane probes one split point,
// ballot/popc selects the sub-interval. Range shrinks 64x per round ->
// 131072 resolves in 4 dependent loads (vs 17 for binary search).
// ---------------------------------------------------------------------------
__device__ __forceinline__ int lower_bound_wave(const int* __restrict__ batch,
                                                int target, int lane)
{
    int lo = 0, hi = N_NODES;
    while (lo < hi) {
        int span  = hi - lo;
        int chunk = (span + 63) >> 6;          // ceil(span/64)
        int idx   = lo + lane * chunk;         // lane 0 probes lo
        bool p    = (idx < hi) && (batch[idx] < target);
        unsigned long long m = __ballot(p);
        int c = __popcll(m);                   // prefix-true count
        if (c == 0) return lo;                 // batch[lo] >= target
        int nhi = (c < 64) ? (lo + c * chunk) : hi;
        lo = lo + (c - 1) * chunk + 1;
        hi = (nhi < hi) ? nhi : hi;
    }
    return lo;
}

// ---------------------------------------------------------------------------
// Kernel 2: one wave per segment; rank sort; quantiles; fused final MLP.
// (unchanged from R6 — proven, absmax 0)
// ---------------------------------------------------------------------------
__global__ __launch_bounds__(256)
void aggregate_kernel(const float* __restrict__ v,
                      const int* __restrict__ batch,
                      const float* __restrict__ Wm1,
                      const float* __restrict__ bm1,
                      const float* __restrict__ Wm2,
                      const float* __restrict__ bm2,
                      float* __restrict__ out)
{
    __shared__ float vals[4][SEGCAP];
    __shared__ float sorted[4][SEGCAP];
    __shared__ float agg_s[4][12];

    const int t    = threadIdx.x;
    const int wid  = t >> 6;
    const int lane = t & 63;
    const int b    = blockIdx.x * 4 + wid;

    const int start = lower_bound_wave(batch, b, lane);
    const int end   = lower_bound_wave(batch, b + 1, lane);
    int cnt = end - start;
    if (cnt > SEGCAP) cnt = SEGCAP;

    float lsum = 0.0f;
    for (int i = lane; i < cnt; i += 64) {
        float x = v[start + i];
        vals[wid][i] = x;
        lsum += x;
    }
    #pragma unroll
    for (int o = 32; o; o >>= 1) lsum += __shfl_xor(lsum, o);
    __syncthreads();

    for (int i = lane; i < cnt; i += 64) {
        float xi = vals[wid][i];
        int r = 0;
        for (int j = 0; j < cnt; ++j) {
            float xj = vals[wid][j];
            r += (xj < xi) || (xj == xi && j < i);
        }
        sorted[wid][r] = xi;
    }
    __syncthreads();

    if (cnt > 0) {
        float cntf = (float)cnt;
        if (lane == 9)  agg_s[wid][0] = lsum / cntf;
        if (lane == 10) agg_s[wid][1] = sorted[wid][cnt - 1];
        if (lane == 11) agg_s[wid][2] = sorted[wid][0];
        if (lane < 9) {
            float q   = (float)(lane + 1) * 0.1f;
            float pos = q * (cntf - 1.0f);
            float f   = floorf(pos);
            float frac = pos - f;
            int loi = (int)f;
            int hii = loi + 1; if (hii > cnt - 1) hii = cnt - 1;
            agg_s[wid][3 + lane] = sorted[wid][loi] + frac * (sorted[wid][hii] - sorted[wid][loi]);
        }
    } else {
        if (lane < 12) agg_s[wid][lane] = 0.0f;
    }
    __syncthreads();

    float term = 0.0f;
    #pragma unroll
    for (int rj = 0; rj < 2; ++rj) {
        int j = lane + 64 * rj;
        float h = bm1[j];
        #pragma unroll
        for (int k = 0; k < 12; ++k) h = fmaf(agg_s[wid][k], Wm1[k * H_DIM + j], h);
        h = h > 0.0f ? h : 0.0f;
        term = fmaf(h, Wm2[j], term);
    }
    #pragma unroll
    for (int o = 32; o; o >>= 1) term += __shfl_xor(term, o);
    if (lane == 0) out[b] = term + bm2[0];
}

// ---------------------------------------------------------------------------
extern "C" void kernel_launch(void* const* d_in, const int* in_sizes, int n_in,
                              void* d_out, int out_size, void* d_ws, size_t ws_size,
                              hipStream_t stream)
{
    const float* emb    = (const float*)d_in[0];
    const int*   batch  = (const int*)d_in[1];
    const float* W_lins = (const float*)d_in[2];
    const float* b_lins = (const float*)d_in[3];
    const float* W1     = (const float*)d_in[4];
    const float* b1     = (const float*)d_in[5];
    const float* W2     = (const float*)d_in[6];
    const float* b2     = (const float*)d_in[7];
    const float* Wm1    = (const float*)d_in[8];
    const float* bm1    = (const float*)d_in[9];
    const float* Wm2    = (const float*)d_in[10];
    const float* bm2    = (const float*)d_in[11];

    float* out  = (float*)d_out;
    float* vbuf = (float*)d_ws;   // 512 KB scratch

    node_readout_kernel<<<N_NODES / M_TILE, 256, 0, stream>>>(
        emb, W_lins, b_lins, W1, b1, W2, b2, vbuf);
    aggregate_kernel<<<B_SEG / 4, 256, 0, stream>>>(
        vbuf, batch, Wm1, bm1, Wm2, bm2, out);
}